// Round 1
// 1143.009 us; speedup vs baseline: 1.0339x; 1.0339x over previous
//
#include <hip/hip_runtime.h>

// Problem dims (fixed by setup_inputs): x:(8,64,512,512) f32, flow:(8,2,512,512) f32
#define BB 8
#define CC 64
#define HH 512
#define WW 512
#define CG 16              // channels per block
#define NCG (CC / CG)      // 4 channel groups
#define NXCD 8

typedef float f4 __attribute__((ext_vector_type(4)));

// Block = 256 threads = half a row of one (b, channel-group).
// Grid order (after swizzle): per-XCD contiguous chunk = one batch;
// within chunk: cg outer, rows inner -> in-flight gather working set per XCD
// ~ 128 rows x 16 ch x 2KB ~= 4.3 MB ~= one XCD's L2.
__global__ __launch_bounds__(256) void align2d_warp_kernel(
    const float* __restrict__ x,
    const float* __restrict__ flow,
    float* __restrict__ out)
{
    const int nwg = BB * NCG * HH * 2;            // 32768
    const int cpx = nwg / NXCD;                   // 4096 (divisible -> bijective)
    const int bid = blockIdx.x;
    // XCD-aware swizzle: blocks with bid % 8 == k (round-robin to XCD k)
    // get the contiguous work chunk [k*cpx, (k+1)*cpx).
    const int wg  = (bid % NXCD) * cpx + bid / NXCD;

    const int b     = wg / (NCG * HH * 2);
    int rem         = wg % (NCG * HH * 2);
    const int cg    = rem / (HH * 2);             // cg outer
    rem             = rem % (HH * 2);
    const int h     = rem >> 1;                   // rows inner
    const int whalf = rem & 1;
    const int w     = whalf * 256 + threadIdx.x;

    // flow layout: (B, 2, H, W)
    const int pix = h * WW + w;
    const float fx = flow[((size_t)b * 2 + 0) * (HH * WW) + pix];
    const float fy = flow[((size_t)b * 2 + 1) * (HH * WW) + pix];

    // border-clamped bilinear coords (mirrors reference semantics)
    float px = fminf(fmaxf((float)w + fx, 0.0f), (float)(WW - 1));
    float py = fminf(fmaxf((float)h + fy, 0.0f), (float)(HH - 1));
    float x0f = floorf(px);
    float y0f = floorf(py);
    float wx = px - x0f;
    float wy = py - y0f;
    int x0 = (int)x0f;                 // in [0, W-1] after clamp
    int y0 = (int)y0f;
    int x1 = min(x0 + 1, WW - 1);
    int y1 = min(y0 + 1, HH - 1);

    const int o00 = y0 * WW + x0;
    const int o01 = y0 * WW + x1;
    const int o10 = y1 * WW + x0;
    const int o11 = y1 * WW + x1;

    const float w00 = (1.0f - wx) * (1.0f - wy);
    const float w01 = wx * (1.0f - wy);
    const float w10 = (1.0f - wx) * wy;
    const float w11 = wx * wy;

    const float* xb = x   + ((size_t)b * CC + (size_t)cg * CG) * (HH * WW);
    float*       ob = out + ((size_t)b * CC + (size_t)cg * CG) * (HH * WW) + pix;

    #pragma unroll 8
    for (int c = 0; c < CG; ++c) {
        const float* p = xb + (size_t)c * (HH * WW);
        float v = p[o00] * w00 + p[o01] * w01 + p[o10] * w10 + p[o11] * w11;
        // keep the 537 MB store stream out of L2/L3 so gather lines survive
        __builtin_nontemporal_store(v, ob + (size_t)c * (HH * WW));
    }
}

// pass-through copy of flow into the tail of d_out (16 MiB, float4, nontemporal)
__global__ __launch_bounds__(256) void align2d_flowcopy_kernel(
    const f4* __restrict__ flow, f4* __restrict__ out)
{
    const int i = blockIdx.x * blockDim.x + threadIdx.x;
    f4 v = __builtin_nontemporal_load(flow + i);
    __builtin_nontemporal_store(v, out + i);
}

extern "C" void kernel_launch(void* const* d_in, const int* in_sizes, int n_in,
                              void* d_out, int out_size, void* d_ws, size_t ws_size,
                              hipStream_t stream) {
    const float* x    = (const float*)d_in[0];
    const float* flow = (const float*)d_in[1];
    float* out = (float*)d_out;

    const int nwg = BB * NCG * HH * 2;             // 32768 blocks
    align2d_warp_kernel<<<nwg, 256, 0, stream>>>(x, flow, out);

    const int nflow4 = (BB * 2 * HH * WW) / 4;     // 1,048,576 float4
    float* out_flow = out + (size_t)BB * CC * HH * WW;
    align2d_flowcopy_kernel<<<nflow4 / 256, 256, 0, stream>>>(
        (const f4*)flow, (f4*)out_flow);
}